// Round 4
// baseline (313.938 us; speedup 1.0000x reference)
//
#include <hip/hip_runtime.h>
#include <stdint.h>
#include <stddef.h>

// DIM=2048, H=16, Q_RANK=768, KV_RANK=512, QK_STATIC=128, QK_ROT=64,
// QK_TOTAL=192, V_DIM=128, BS=2, SEQ=1024, NTOK=2048.
// Score contraction absorbed on the K side: kh[b,h] = kvn @ W_k[h]^T (128-dim),
// so scores = [q_static | q_rot] . [kh | k_rot] over 192 dims (vs 576).

typedef __attribute__((ext_vector_type(8))) short bf16x8;
typedef __attribute__((ext_vector_type(4))) float f32x4;

__device__ inline float b2f(unsigned short v){
    union { unsigned u; float f; } x; x.u = ((unsigned)v) << 16; return x.f;
}
__device__ inline unsigned short f2b(float f){
    union { float f; unsigned u; } x; x.f = f;
    unsigned r = x.u + 0x7fffu + ((x.u >> 16) & 1u);
    return (unsigned short)(r >> 16);
}

// async global->LDS, 16B per lane. LDS dest = wave-uniform base + lane*16.
__device__ __forceinline__ void gl2lds16(const unsigned short* g, unsigned short* l){
    __builtin_amdgcn_global_load_lds(
        (__attribute__((address_space(1))) void*)const_cast<unsigned short*>(g),
        (__attribute__((address_space(3))) void*)l,
        16, 0, 0);
}

// C[M,N] = alpha*(A @ B^T) + bias, bf16 A/B, fp32 accumulate.
// A[M,K] lda, B[N,K] ldb. 128x128 tile, BK=32, 4 waves 2x2, 16x16x32 MFMA.
// 3-deep global_load_lds pipeline (vmcnt(4) waits, raw s_barrier, no full drain).
// LDS bank swizzle: stage global chunk (lane&3)^((lane>>3)&3); reads use chunk
// g^((row>>1)&3) -> all 8 (row&1,chunk) bank-groups covered.
// causal bit0: compact triangular tile decode (index = bm), -1e9 above diagonal.
// causal bit1: K = min(K, m0+128).
// causal bit2: z-first grid (z=blockIdx.x) for XCD/L2 locality.
template<typename TC>
__global__ __launch_bounds__(256) void mfma_gemm_bt(
    const unsigned short* __restrict__ A, const unsigned short* __restrict__ B,
    const float* __restrict__ bias, TC* __restrict__ C,
    int M, int N, int K, int lda, int ldb, int ldc,
    int zdiv, long sA_hi, long sA_lo, long sB_hi, long sB_lo, long sC_hi, long sC_lo,
    float alpha, int causal)
{
    int z, bm, bn;
    if (causal & 4){ z = blockIdx.x; bm = blockIdx.y; bn = blockIdx.z; }
    else           { z = blockIdx.z; bm = blockIdx.y; bn = blockIdx.x; }
    int m0, n0;
    if (causal & 1){
        int i = bm;
        int mt = (int)((sqrtf(8.f * i + 1.f) - 1.f) * 0.5f);
        while ((mt + 1) * (mt + 2) / 2 <= i) ++mt;
        while (mt * (mt + 1) / 2 > i) --mt;
        n0 = (i - mt * (mt + 1) / 2) * 128;
        m0 = mt * 128;
    } else { m0 = bm * 128; n0 = bn * 128; }
    if (causal & 2) K = min(K, m0 + 128);

    __shared__ unsigned short As[3][4096];
    __shared__ unsigned short Bs[3][4096];
    const int zh = z / zdiv, zl = z % zdiv;
    A += (size_t)zh * sA_hi + (size_t)zl * sA_lo;
    B += (size_t)zh * sB_hi + (size_t)zl * sB_lo;
    C += (size_t)zh * sC_hi + (size_t)zl * sC_lo;

    const int tid = threadIdx.x, w = tid >> 6, lane = tid & 63;
    const int wm = w >> 1, wn = w & 1;

    const int srow = w * 32 + (lane >> 2);
    const int schunk = ((lane & 3) ^ ((lane >> 3) & 3)) * 8;   // row-bit-1/2 swizzle
    const unsigned short* gA = A + (size_t)(m0 + srow) * lda + schunk;
    const unsigned short* gB = B + (size_t)(n0 + srow) * ldb + schunk;

    const int ktiles = K >> 5;
    auto stage = [&](int buf, int kt){
        const int k0 = kt << 5;
        gl2lds16(gA + k0,            &As[buf][w * 1024]);
        gl2lds16(gA + k0 + 16 * lda, &As[buf][w * 1024 + 512]);
        gl2lds16(gB + k0,            &Bs[buf][w * 1024]);
        gl2lds16(gB + k0 + 16 * ldb, &Bs[buf][w * 1024 + 512]);
    };
    stage(0, 0);
    if (ktiles > 1) stage(1, 1);

    f32x4 acc[4][4] = {};
    const int lm = lane & 15;
    const int kq = (((lane >> 4) ^ (lm >> 1)) & 3) * 8;        // matches stage swizzle

    int cur = 0;
    for (int kt = 0; kt < ktiles; ++kt){
        if (kt + 1 < ktiles) __builtin_amdgcn_s_waitcnt(0xF74);
        else                 __builtin_amdgcn_s_waitcnt(0xF70);
        __builtin_amdgcn_s_barrier();
        __asm__ volatile("" ::: "memory");
        if (kt + 2 < ktiles) stage(cur >= 1 ? cur - 1 : 2, kt + 2);
        bf16x8 af[4], bfr[4];
        #pragma unroll
        for (int i = 0; i < 4; ++i)
            af[i] = *(const bf16x8*)&As[cur][(wm * 64 + i * 16 + lm) * 32 + kq];
        #pragma unroll
        for (int j = 0; j < 4; ++j)
            bfr[j] = *(const bf16x8*)&Bs[cur][(wn * 64 + j * 16 + lm) * 32 + kq];
        #pragma unroll
        for (int i = 0; i < 4; ++i)
            #pragma unroll
            for (int j = 0; j < 4; ++j)
                acc[i][j] = __builtin_amdgcn_mfma_f32_16x16x32_bf16(af[i], bfr[j], acc[i][j], 0, 0, 0);
        __asm__ volatile("" ::: "memory");
        cur = (cur == 2) ? 0 : cur + 1;
    }

    // C/D layout: col = lane&15, row = (lane>>4)*4 + reg
    #pragma unroll
    for (int i = 0; i < 4; ++i){
        const int m = m0 + wm * 64 + i * 16 + (lane >> 4) * 4;
        #pragma unroll
        for (int j = 0; j < 4; ++j){
            const int n = n0 + wn * 64 + j * 16 + lm;
            if (n < N){
                const float bb = bias ? bias[n] : 0.f;
                #pragma unroll
                for (int r = 0; r < 4; ++r){
                    float v = acc[i][j][r] * alpha + bb;
                    if ((causal & 1) && n > m + r) v = -1e9f;
                    if constexpr (sizeof(TC) == 2)
                        C[(size_t)(m + r) * ldc + n] = (TC)f2b(v);
                    else
                        C[(size_t)(m + r) * ldc + n] = (TC)v;
                }
            }
        }
    }
}

// Work schedule for flash_attn (equal-work split + backfill).
// Per z: 16 q-tiles; tiles with nkt>=5 (mt 8..15) split into two KV-halves.
// 24 items per z, loads {4x8, 3x10, 2x4, 1x2}, sorted heavy-first by s.
// Entry pack: mt | (kt0<<4) | (kt1<<8).
__constant__ unsigned short flash_sched[24] = {
    0x040F, 0x084F, 0x040E, 0x084E, 0x040D, 0x040C, 0x0407, 0x0406,   // load 4
    0x074D, 0x074C, 0x030B, 0x063B, 0x030A, 0x063A, 0x0309, 0x0308,   // load 3
    0x0305, 0x0304,                                                    // load 3
    0x0539, 0x0538, 0x0203, 0x0202,                                    // load 2
    0x0101, 0x0100};                                                   // load 1

// Fused causal attention v8: score dim = 192 (K-side absorption).
// 768 equal-work blocks (max 4 kv-tile iters; q-tiles with nkt>=5 split into
// two KV-halves, f32 partials combined by combine_ctx).
//
// v5/v6/v7 all measured OccupancyPercent pinned at ~12.5% (= 1 block/CU)
// despite 2x74240B nominally fitting 160KB LDS -> hypothesis: a workgroup
// using >64KB LDS cannot co-reside on a CU. v8: Q moved from LDS into 12
// bf16x8 registers per thread (loaded once, per-lane global addresses match
// the MFMA A-fragment layout directly; kills the stage + 12 ds_read_b128
// per kv-tile). LDS = 3 K-buffers + lrow = 49,664B -> up to 3 blocks/CU.
// vm-queue arithmetic unchanged: Q's 12 loads are the oldest entries and
// drain at the first c=0 vmcnt(24), exactly where Qs staging used to.
// Keeps: chunk0 cross-tile prefetch (Ks[2]), counted vmcnt (24/20/16),
// lgkm-only barriers, deferred V drain (vmcnt(4)/(0) at PV), setprio.
__global__ __launch_bounds__(256) void flash_attn(
    const unsigned short* __restrict__ qu,    // [2048][3072], q_rot slices roped
    const unsigned short* __restrict__ khcat, // [32][1024][192] = [kh | k_rot]
    const unsigned short* __restrict__ vhT,   // [2][16][128][1024]
    unsigned short* __restrict__ ctx,         // [2048][2048]
    float* __restrict__ Opart,                // [512][64][128] f32 partials
    float* __restrict__ lpart)                // [512][64] f32 row sums
{
    const int t = blockIdx.x;
    const int r8 = t & 7, u = t >> 3;
    const int s = u >> 2, zg = u & 3;
    const int z = zg * 8 + r8;
    const unsigned e = flash_sched[s];
    const int mt  = e & 15;
    const int kt0 = (e >> 4) & 15;
    const int kt1 = (int)(e >> 8);
    const int b = z >> 4, h = z & 15;
    const int m0 = mt * 64;

    __shared__ char smem[49664];
    unsigned short (*Ks)[8192] = (unsigned short (*)[8192])smem;  // 3 x 128x64
    unsigned short* Ps = (unsigned short*)smem;                   // 64x136, aliases Ks[0..1]
    float* lrow = (float*)(smem + 49152);                         // [2][64]

    const unsigned short* kB = khcat + (size_t)z * 196608;
    const unsigned short* vB = vhT + (size_t)z * 131072;

    const int tid = threadIdx.x, w = tid >> 6, lane = tid & 63;
    const int wm = w >> 1, wn = w & 1;
    const int lm = lane & 15, g = lane >> 4;
    const int kq = g * 8;

    if (tid < 128) lrow[tid] = 0.f;

    const int srow8 = lane >> 3;              // 0..7
    const int soff8 = ((lane & 7) ^ (lane >> 3)) * 8;  // swizzled global chunk

    // Q -> registers, once. qf[c][i][kk] = Q[m0+wm*32+i*16+lm][c*64+kk*32+g*8..+8]
    // (per-lane addresses ARE the MFMA A-fragment layout; no LDS round-trip).
    const unsigned short* qRow = qu + (size_t)(b * 1024 + m0 + wm * 32 + lm) * 3072
                                 + h * 192;
    bf16x8 qf[3][2][2];
    #pragma unroll
    for (int c = 0; c < 3; ++c)
        #pragma unroll
        for (int i = 0; i < 2; ++i)
            #pragma unroll
            for (int kk = 0; kk < 2; ++kk)
                qf[c][i][kk] = *(const bf16x8*)(qRow + (size_t)i * 16 * 3072
                                                + c * 64 + (kk * 4 + g) * 8);
    __asm__ volatile("" ::: "memory");        // Q loads oldest in vm queue

    // K chunks with FIXED buffer roles: chunk0 -> Ks[2] (prefetched one
    // kv-tile ahead), chunk1 -> Ks[0], chunk2 -> Ks[1].
    auto stageK = [&](int buf, int kt, int c){
        const unsigned short* gK = kB + (size_t)(kt * 128 + w * 32 + srow8) * 192
                                   + c * 64 + soff8;
        gl2lds16(gK,            &Ks[buf][w * 2048]);
        gl2lds16(gK + 8 * 192,  &Ks[buf][w * 2048 + 512]);
        gl2lds16(gK + 16 * 192, &Ks[buf][w * 2048 + 1024]);
        gl2lds16(gK + 24 * 192, &Ks[buf][w * 2048 + 1536]);
    };
    stageK(2, kt0, 0);                        // chunk0 of first tile

    f32x4 Oacc[2][4] = {};
    const float scl = 0.07216878364870322f;   // 1/sqrt(192)

    for (int kt = kt0; kt < kt1; ++kt){
        stageK(0, kt, 1);                     // chunk1 -> buf0 (Ps dead now)
        stageK(1, kt, 2);                     // chunk2 -> buf1
        __asm__ volatile("" ::: "memory");    // pin V loads AFTER K stages
        bf16x8 vfr[4][4];
        #pragma unroll
        for (int j = 0; j < 4; ++j)
            #pragma unroll
            for (int kc = 0; kc < 4; ++kc)
                vfr[j][kc] = *(const bf16x8*)(vB + (size_t)(wn * 64 + j * 16 + lm) * 1024
                                              + kt * 128 + kc * 32 + kq);
        __asm__ volatile("" ::: "memory");

        // vm queue (oldest first), steady state: pf-chunk0(4) (first kt:
        // Q(12)+chunk0(4)), chunk1(4), chunk2(4), V(16).
        f32x4 S[2][4] = {};
        #pragma unroll
        for (int c = 0; c < 3; ++c){
            if      (c == 0) __builtin_amdgcn_s_waitcnt(0x4F78);  // vmcnt(24): chunk0 (+Q) in
            else if (c == 1) __builtin_amdgcn_s_waitcnt(0x4F74);  // vmcnt(20): chunk1 in
            else             __builtin_amdgcn_s_waitcnt(0x4F70);  // vmcnt(16): chunk2 in, V in flight
            __builtin_amdgcn_s_barrier();
            __asm__ volatile("" ::: "memory");
            const int bufc = (c == 0) ? 2 : (c - 1);
            const int rs7 = lm & 7;
            bf16x8 bfr[4][2];
            #pragma unroll
            for (int j = 0; j < 4; ++j)
                #pragma unroll
                for (int kk = 0; kk < 2; ++kk)
                    bfr[j][kk] = *(const bf16x8*)&Ks[bufc][(wn * 64 + j * 16 + lm) * 64
                                                           + (((kk * 4 + g) ^ rs7) * 8)];
            __builtin_amdgcn_s_setprio(1);
            #pragma unroll
            for (int kk = 0; kk < 2; ++kk)
                #pragma unroll
                for (int i = 0; i < 2; ++i)
                    #pragma unroll
                    for (int j = 0; j < 4; ++j)
                        S[i][j] = __builtin_amdgcn_mfma_f32_16x16x32_bf16(qf[c][i][kk], bfr[j][kk], S[i][j], 0, 0, 0);
            __builtin_amdgcn_s_setprio(0);
            __asm__ volatile("" ::: "memory");
        }
        // all QK reads of Ks done -> Ps (alias) writable. lgkm-only barrier:
        // keep the vm queue (V + upcoming prefetch) alive across it.
        __builtin_amdgcn_s_waitcnt(0xC07F);   // lgkmcnt(0), vmcnt untouched
        __builtin_amdgcn_s_barrier();
        __asm__ volatile("" ::: "memory");
        if (kt + 1 < kt1) stageK(2, kt + 1, 0);   // prefetch next chunk0 -> buf2

        // softmax numerator (global-index causal mask on the diagonal tile);
        // row sums; P -> LDS (aliased on Ks[0..1]) in [m][k] layout.
        const bool diag = (kt == (mt >> 1));
        #pragma unroll
        for (int i = 0; i < 2; ++i){
            float rs[4] = {0.f, 0.f, 0.f, 0.f};
            #pragma unroll
            for (int j = 0; j < 4; ++j){
                const int nloc = wn * 64 + j * 16 + lm;
                #pragma unroll
                for (int r = 0; r < 4; ++r){
                    const int mloc = wm * 32 + i * 16 + g * 4 + r;
                    float p = __expf(S[i][j][r] * scl);
                    if (diag && (kt * 128 + nloc) > (m0 + mloc)) p = 0.f;
                    rs[r] += p;
                    Ps[mloc * 136 + nloc] = f2b(p);
                }
            }
            #pragma unroll
            for (int r = 0; r < 4; ++r){
                rs[r] += __shfl_xor(rs[r], 1, 64);
                rs[r] += __shfl_xor(rs[r], 2, 64);
                rs[r] += __shfl_xor(rs[r], 4, 64);
                rs[r] += __shfl_xor(rs[r], 8, 64);
            }
            if (lm == 0){
                #pragma unroll
                for (int r = 0; r < 4; ++r)
                    lrow[wn * 64 + wm * 32 + i * 16 + g * 4 + r] += rs[r];
            }
        }
        __asm__ volatile("" ::: "memory");
        __builtin_amdgcn_s_waitcnt(0xC07F);   // Ps + lrow visible
        __builtin_amdgcn_s_barrier();
        __asm__ volatile("" ::: "memory");

        // O += P @ V^T  (A = Ps rows, B = vfr registers). V drained here
        // (in-order vm retirement; prefetched chunk0 may stay in flight).
        if (kt + 1 < kt1) __builtin_amdgcn_s_waitcnt(0xF74);  // vmcnt(4)
        else              __builtin_amdgcn_s_waitcnt(0xF70);  // vmcnt(0)
        #pragma unroll
        for (int kc = 0; kc < 4; ++kc){
            bf16x8 pa[2];
            #pragma unroll
            for (int i = 0; i < 2; ++i)
                pa[i] = *(const bf16x8*)&Ps[(wm * 32 + i * 16 + lm) * 136 + kc * 32 + kq];
            __builtin_amdgcn_s_setprio(1);
            #pragma unroll
            for (int i = 0; i < 2; ++i)
                #pragma unroll
                for (int j = 0; j < 4; ++j)
                    Oacc[i][j] = __builtin_amdgcn_mfma_f32_16x16x32_bf16(pa[i], vfr[j][kc], Oacc[i][j], 0, 0, 0);
            __builtin_amdgcn_s_setprio(0);
        }
        __asm__ volatile("" ::: "memory");
        __builtin_amdgcn_s_waitcnt(0xC07F);   // Ps reads done -> next kt restages buf0/1
        __builtin_amdgcn_s_barrier();
        __asm__ volatile("" ::: "memory");
    }

    if (mt < 8){
        // unsplit: normalize and store ctx[(b*1024+m0+row)][h*128 + col]
        unsigned short* cBase = ctx + ((size_t)(b * 1024 + m0)) * 2048 + h * 128;
        #pragma unroll
        for (int i = 0; i < 2; ++i){
            #pragma unroll
            for (int r = 0; r < 4; ++r){
                const int row = wm * 32 + i * 16 + g * 4 + r;
                const float inv = 1.f / (lrow[row] + lrow[64 + row]);
                #pragma unroll
                for (int j = 0; j < 4; ++j){
                    const int col = wn * 64 + j * 16 + lm;
                    cBase[(size_t)row * 2048 + col] = f2b(Oacc[i][j][r] * inv);
                }
            }
        }
    } else {
        // split half: raw f32 partial O + row sums -> combine_ctx
        const int p = ((z << 3) + (mt - 8)) * 2 + (kt0 ? 1 : 0);
        float* Ob = Opart + (size_t)p * 8192;
        #pragma unroll
        for (int i = 0; i < 2; ++i){
            #pragma unroll
            for (int r = 0; r < 4; ++r){
                const int row = wm * 32 + i * 16 + g * 4 + r;
                #pragma unroll
                for (int j = 0; j < 4; ++j){
                    const int col = wn * 64 + j * 16 + lm;
                    Ob[row * 128 + col] = Oacc[i][j][r];
                }
            }
        }
        if (wn == 0 && lm == 0){
            #pragma unroll
            for (int i = 0; i < 2; ++i)
                #pragma unroll
                for (int r = 0; r < 4; ++r){
                    const int row = wm * 32 + i * 16 + g * 4 + r;
                    lpart[p * 64 + row] = lrow[row] + lrow[64 + row];
                }
        }
    }
}

// Combine split-attention halves: ctx = (Oa + Ob) / (la + lb), bf16.
// One block per (z, mt-8): 64 rows x 128 cols.
__global__ __launch_bounds__(256) void combine_ctx(
    const float* __restrict__ Opart, const float* __restrict__ lpart,
    unsigned short* __restrict__ ctx)
{
    const int pb = blockIdx.x;                // z*8 + (mt-8)
    const int z = pb >> 3, mt = (pb & 7) + 8;
    const int b = z >> 4, h = z & 15;
    const int tid = threadIdx.x;
    const float* Oa = Opart + (size_t)(2 * pb) * 8192;
    const float* Ob = Oa + 8192;
    const float* la = lpart + 2 * pb * 64;    // [0..63]=half0, [64..127]=half1
    unsigned short* cBase = ctx + ((size_t)(b * 1024 + mt * 64)) * 2048 + h * 128;
    #pragma unroll
    for (int i = 0; i < 8; ++i){
        const int idx4 = i * 256 + tid;       // 0..2047 float4 index
        const int row = idx4 >> 5, c0 = (idx4 & 31) * 4;
        float4 a  = *(const float4*)(Oa + row * 128 + c0);
        float4 bv = *(const float4*)(Ob + row * 128 + c0);
        const float inv = 1.f / (la[row] + la[64 + row]);
        *(ushort4*)(cBase + (size_t)row * 2048 + c0) = make_ushort4(
            f2b((a.x + bv.x) * inv), f2b((a.y + bv.y) * inv),
            f2b((a.z + bv.z) * inv), f2b((a.w + bv.w) * inv));
    }
}

// One launch casting all six f32 weight/activation blobs to bf16.
__global__ __launch_bounds__(256) void cast_all(
    const float* __restrict__ s0, unsigned short* __restrict__ d0,   // x      4194304
    const float* __restrict__ s1, unsigned short* __restrict__ d1,   // q_down 1572864
    const float* __restrict__ s2, unsigned short* __restrict__ d2,   // q_up   2359296
    const float* __restrict__ s3, unsigned short* __restrict__ d3,   // kv_down1179648
    const float* __restrict__ s4, unsigned short* __restrict__ d4,   // kv_up  2097152
    const float* __restrict__ s5, unsigned short* __restrict__ d5)   // out_w  4194304
{
    long i = (long)(blockIdx.x * 256 + threadIdx.x) * 4;
    const float* s; unsigned short* d; long off;
    if      (i <  4194304L){ s = s0; d = d0; off = i; }
    else if (i <  5767168L){ s = s1; d = d1; off = i -  4194304L; }
    else if (i <  8126464L){ s = s2; d = d2; off = i -  5767168L; }
    else if (i <  9306112L){ s = s3; d = d3; off = i -  8126464L; }
    else if (i < 11403264L){ s = s4; d = d4; off = i -  9306112L; }
    else                   { s = s5; d = d5; off = i - 11403264L; }
    float4 v = *(const float4*)(s + off);
    *(ushort4*)(d + off) = make_ushort4(f2b(v.x), f2b(v.y), f2b(v.z), f2b(v.w));
}

// Fused down-proj epilogue. p = [4][2048][1344] bf16 split-K partials.
__global__ __launch_bounds__(256) void fused_down_post(
    const unsigned short* __restrict__ p,
    const float* __restrict__ q_down_b, const float* __restrict__ kv_down_b,
    const float* __restrict__ q_norm_s, const float* __restrict__ kv_norm_s,
    unsigned short* __restrict__ qn, unsigned short* __restrict__ kcat)
{
    __shared__ float row[1344];
    __shared__ float red[4];
    const int t = blockIdx.x, tid = threadIdx.x;
    const long S = 2752512L; // 2048*1344
    const unsigned short* b0 = p + (size_t)t * 1344;
    for (int c = tid; c < 1344; c += 256){
        float v = b2f(b0[c]) + b2f(b0[c + S]) + b2f(b0[c + 2*S]) + b2f(b0[c + 3*S]);
        v += (c < 768) ? q_down_b[c] : kv_down_b[c - 768];
        row[c] = v;
    }
    __syncthreads();
    const int lane = tid & 63, w = tid >> 6;
    float ss = 0.f;
    for (int c = tid; c < 768; c += 256){ float v = row[c]; ss += v * v; }
    #pragma unroll
    for (int o = 32; o > 0; o >>= 1) ss += __shfl_xor(ss, o, 64);
    if (lane == 0) red[w] = ss;
    __syncthreads();
    const float inv1 = rsqrtf((red[0]+red[1]+red[2]+red[3]) / 768.f + 1e-6f);
    __syncthreads();
    ss = 0.f;
    for (int c = tid; c < 512; c += 256){ float v = row[768 + c]; ss += v * v; }
    #pragma unroll
    for (int o = 32; o > 0; o >>= 1) ss += __shfl_xor(ss, o, 64);
    if (lane == 0) red[w] = ss;
    __syncthreads();
    const float inv2 = rsqrtf((red[0]+red[1]+red[2]+red[3]) / 512.f + 1e-6f);
    for (int c = tid; c < 768; c += 256)
        qn[(size_t)t * 768 + c] = f2b(q_norm_s[c] * row[c] * inv1);
    for (int c = tid; c < 512; c += 256)
        kcat[(size_t)t * 576 + c] = f2b(kv_norm_s[c] * row[768 + c] * inv2);
    if (tid < 64){
        const int d = tid, s = t & 1023;
        float x  = row[1280 + d];
        float xp = (d < 32) ? -row[1280 + d + 32] : row[1280 + d - 32];
        float ang = (float)s * powf(10000.f, -(float)(2 * (d & 31)) / 64.f);
        kcat[(size_t)t * 576 + 512 + d] = f2b(x * cosf(ang) + xp * sinf(ang));
    }
}

// out = p[0] + p[1] + bias (p bf16 partials, out f32 2048x2048)
__global__ __launch_bounds__(256) void reduce_out(
    const unsigned short* __restrict__ p, const float* __restrict__ bias,
    float* __restrict__ out)
{
    const long S = 4194304L;
    long i = (long)(blockIdx.x * 256 + threadIdx.x) * 4;
    ushort4 a = *(const ushort4*)(p + i);
    ushort4 b = *(const ushort4*)(p + i + S);
    float4 bb = *(const float4*)(bias + (i & 2047));
    float4 r = make_float4(b2f(a.x) + b2f(b.x) + bb.x, b2f(a.y) + b2f(b.y) + bb.y,
                           b2f(a.z) + b2f(b.z) + bb.z, b2f(a.w) + b2f(b.w) + bb.w);
    *(float4*)(out + i) = r;
}

// Combined: (1) pairwise in-place RoPE on qu's q_rot slices (thread owns the
// (d, d+32) pair -> no race); (2) broadcast roped k_rot into khcat cols 128..192.
__global__ __launch_bounds__(256) void rope_q_krot(
    unsigned short* __restrict__ qu,          // [2048][3072]
    const unsigned short* __restrict__ kcat,  // [2048][576]
    unsigned short* __restrict__ khcat)       // [32][1024][192]
{
    long idx = (long)blockIdx.x * 256 + threadIdx.x;
    if (idx < 1048576L){
        const int d   = idx & 31;
        const int h   = (idx >> 5) & 15;
        const int tok = idx >> 9;
        const int s   = tok & 1023;
        unsigned short* base = qu + (size_t)tok * 3072 + h * 192 + 128;
        float x1 = b2f(base[d]), x2 = b2f(base[d + 32]);
        float ang = (float)s * powf(10000.f, -(float)d / 32.f);
        float c = cosf(ang), sn = sinf(ang);
        base[d]      = f2b(x1 * c - x2 * sn);
        base[d + 32] = f2b(x2 * c + x1 * sn);
    } else {
        idx -= 1048576L;
        const int d   = idx & 63;
        const int h   = (idx >> 6) & 15;
        const int tok = (int)(idx >> 10);
        const int bb  = tok >> 10, s = tok & 1023;
        khcat[((size_t)(bb * 16 + h) * 1024 + s) * 192 + 128 + d] =
            kcat[(size_t)tok * 576 + 512 + d];
    }
}

extern "C" void kernel_launch(void* const* d_in, const int* in_sizes, int n_in,
                              void* d_out, int out_size, void* d_ws, size_t ws_size,
                              hipStream_t stream)
{
    const float* x         = (const float*)d_in[0];
    const float* q_down_w  = (const float*)d_in[3];
    const float* q_down_b  = (const float*)d_in[4];
    const float* q_norm_s  = (const float*)d_in[5];
    const float* q_up_w    = (const float*)d_in[6];
    const float* q_up_b    = (const float*)d_in[7];
    const float* kv_down_w = (const float*)d_in[8];
    const float* kv_down_b = (const float*)d_in[9];
    const float* kv_norm_s = (const float*)d_in[10];
    const float* kv_up_w   = (const float*)d_in[11];
    const float* out_w     = (const float*)d_in[12];
    const float* out_b     = (const float*)d_in[13];
    float* out = (float*)d_out;

    // Workspace layout (bytes), peak 100,925,440:
    char* ws = (char*)d_ws;
    unsigned short* kvuw  = (unsigned short*)(ws + 0);           // [4096][512] (w_k rows 0..2047, w_v 2048..4095)
    unsigned short* outw  = (unsigned short*)(ws + 4194304);     // [2048][2048]
    unsigned short* kcat  = (unsigned short*)(ws + 12582912);    // [2048][576]
    unsigned short* vhT   = (unsigned short*)(ws + 14942208);    // [2][16][128][1024]
    unsigned short* khcat = (unsigned short*)(ws + 23330816);    // [32][1024][192]
    unsigned short* ctx   = (unsigned short*)(ws + 35913728);    // [2048][2048] bf16
    unsigned short* qu    = (unsigned short*)(ws + 44302336);    // [2048][3072] (live through flash)
    unsigned short* qn    = (unsigned short*)(ws + 56885248);    // [2048][768]
    unsigned short* p_qkv = (unsigned short*)(ws + 60030976);    // [4][2048][1344] bf16 (dead after fdp)
    unsigned short* p_out = (unsigned short*)(ws + 60030976);    // [2][2048][2048] bf16 (alias p_qkv)
    float*          Opart = (float*)(ws + 60030976);             // [512][8192] f32 (alias p_out; dead before k11)
    float*          lpart = (float*)(ws + 76808192);             // [512][64] f32
    unsigned short* xb    = (unsigned short*)(ws + 82051072);    // [2048][2048]
    unsigned short* qkdw  = (unsigned short*)(ws + 90439680);    // [1408][2048] concat down-proj w
    unsigned short* quw   = (unsigned short*)(ws + 96206848);    // [3072][768]

    dim3 blk(256);

    // casts: q_down -> qkdw rows 0..767, kv_down -> qkdw rows 768..1343
    cast_all<<<15232, blk, 0, stream>>>(x, xb, q_down_w, qkdw, q_up_w, quw,
                                        kv_down_w, qkdw + 1572864, kv_up_w, kvuw, out_w, outw);

    // k1 (split-K x4, bf16 partials): p_qkv[s] = x[:, s*512:] @ qkdw[:, s*512:]^T
    mfma_gemm_bt<unsigned short><<<dim3(11, 16, 4), blk, 0, stream>>>(
        xb, qkdw, nullptr, p_qkv, 2048, 1344, 512, 2048, 2048, 1344,
        4, 0L, 512L, 0L, 512L, 0L, 2752512L, 1.0f, 0);
    // fused: partial-sum + biases + q-rmsnorm -> qn, kv-rmsnorm/rope -> kcat
    fused_down_post<<<2048, blk, 0, stream>>>(p_qkv, q_down_b, kv_down_b,
                                              q_norm_s, kv_norm_s, qn, kcat);
    // k3: qu = bf16(qn @ q_up_w^T + b)  [2048,3072] K=768
    mfma_gemm_bt<unsigned short><<<dim3(24, 16, 1), blk, 0, stream>>>(
        qn, quw, q_up_b, qu, 2048, 3072, 768, 768, 768, 3072,
        1, 0, 0, 0, 0, 0, 0, 1.0f, 0);
    // vhT[b][h] = w_v[h] @ kvn[b]^T  (M=128, N=1024, K=512; z-first grid)
    mfma_gemm_bt<unsigned short><<<dim3(32, 1, 8), blk, 0, stream>>>(
        kvuw + 1048576, kcat, nullptr, vhT, 128, 1024, 512, 512, 576, 1024,
        16, 0L, 65536L, 589824L, 0L, 2097152L, 131072L, 1.0f, 4);
    // kh: khcat[b,h][t][0:128] = kvn[b] @ w_k[h]^T  (M=1024, N=128, K=512; z-first)
    mfma_gemm_bt<unsigned short><<<dim3(32, 8, 1), blk, 0, stream>>>(
        kcat, kvuw, nullptr, khcat, 1024, 128, 512, 576, 512, 192,
        16, 589824L, 0L, 0L, 65536L, 3145728L, 196608L, 1.0f, 4);
    // rope q (in-place on qu) + broadcast roped k_rot into khcat cols 128..192
    rope_q_krot<<<12288, blk, 0, stream>>>(qu, kcat, khcat);
    // fused attention v8: Q-in-registers, LDS 49,664B (multi-block residency)
    flash_attn<<<dim3(768), blk, 0, stream>>>(qu, khcat, vhT, ctx, Opart, lpart);
    // combine split halves for mt>=8 rows
    combine_ctx<<<dim3(256), blk, 0, stream>>>(Opart, lpart, ctx);
    // k11 (split-K x2, bf16 partials): p_out[s] = ctx[:, s*1024:] @ outw[:, s*1024:]^T
    mfma_gemm_bt<unsigned short><<<dim3(16, 16, 2), blk, 0, stream>>>(
        ctx, outw, nullptr, p_out, 2048, 2048, 1024, 2048, 2048, 2048,
        2, 0L, 1024L, 0L, 1024L, 0L, 4194304L, 1.0f, 0);
    // out = p_out[0] + p_out[1] + out_b
    reduce_out<<<4096, blk, 0, stream>>>(p_out, out_b, out);
}

// Round 5
// 293.429 us; speedup vs baseline: 1.0699x; 1.0699x over previous
//
#include <hip/hip_runtime.h>
#include <stdint.h>
#include <stddef.h>

// DIM=2048, H=16, Q_RANK=768, KV_RANK=512, QK_STATIC=128, QK_ROT=64,
// QK_TOTAL=192, V_DIM=128, BS=2, SEQ=1024, NTOK=2048.
// Score contraction absorbed on the K side: kh[b,h] = kvn @ W_k[h]^T (128-dim),
// so scores = [q_static | q_rot] . [kh | k_rot] over 192 dims (vs 576).

typedef __attribute__((ext_vector_type(8))) short bf16x8;
typedef __attribute__((ext_vector_type(4))) float f32x4;

__device__ inline float b2f(unsigned short v){
    union { unsigned u; float f; } x; x.u = ((unsigned)v) << 16; return x.f;
}
__device__ inline unsigned short f2b(float f){
    union { float f; unsigned u; } x; x.f = f;
    unsigned r = x.u + 0x7fffu + ((x.u >> 16) & 1u);
    return (unsigned short)(r >> 16);
}

// async global->LDS, 16B per lane. LDS dest = wave-uniform base + lane*16.
__device__ __forceinline__ void gl2lds16(const unsigned short* g, unsigned short* l){
    __builtin_amdgcn_global_load_lds(
        (__attribute__((address_space(1))) void*)const_cast<unsigned short*>(g),
        (__attribute__((address_space(3))) void*)l,
        16, 0, 0);
}

// Shared GEMM body: C[M,N](+=bias) = alpha*(A @ B^T), bf16 in, fp32 acc.
// 128x128 tile, BK=32, 4 waves 2x2, 16x16x32 MFMA, 3-deep global_load_lds
// pipeline (vmcnt(4) waits, raw s_barrier, no full drain). LDS bank swizzle:
// stage global chunk (lane&3)^((lane>>3)&3); reads use chunk g^((row>>1)&3).
// causal bit0: -1e9 above diagonal in epilogue.
template<typename TC>
static __device__ __forceinline__ void gemm_body(
    unsigned short (*As)[4096], unsigned short (*Bs)[4096],
    const unsigned short* A, const unsigned short* B,
    const float* bias, TC* C,
    int N, int K, int lda, int ldb, int ldc,
    int m0, int n0, float alpha, int causal)
{
    const int tid = threadIdx.x, w = tid >> 6, lane = tid & 63;
    const int wm = w >> 1, wn = w & 1;

    const int srow = w * 32 + (lane >> 2);
    const int schunk = ((lane & 3) ^ ((lane >> 3) & 3)) * 8;   // row-bit-1/2 swizzle
    const unsigned short* gA = A + (size_t)(m0 + srow) * lda + schunk;
    const unsigned short* gB = B + (size_t)(n0 + srow) * ldb + schunk;

    const int ktiles = K >> 5;
    auto stage = [&](int buf, int kt){
        const int k0 = kt << 5;
        gl2lds16(gA + k0,            &As[buf][w * 1024]);
        gl2lds16(gA + k0 + 16 * lda, &As[buf][w * 1024 + 512]);
        gl2lds16(gB + k0,            &Bs[buf][w * 1024]);
        gl2lds16(gB + k0 + 16 * ldb, &Bs[buf][w * 1024 + 512]);
    };
    stage(0, 0);
    if (ktiles > 1) stage(1, 1);

    f32x4 acc[4][4] = {};
    const int lm = lane & 15;
    const int kq = (((lane >> 4) ^ (lm >> 1)) & 3) * 8;        // matches stage swizzle

    int cur = 0;
    for (int kt = 0; kt < ktiles; ++kt){
        if (kt + 1 < ktiles) __builtin_amdgcn_s_waitcnt(0xF74);
        else                 __builtin_amdgcn_s_waitcnt(0xF70);
        __builtin_amdgcn_s_barrier();
        __asm__ volatile("" ::: "memory");
        if (kt + 2 < ktiles) stage(cur >= 1 ? cur - 1 : 2, kt + 2);
        bf16x8 af[4], bfr[4];
        #pragma unroll
        for (int i = 0; i < 4; ++i)
            af[i] = *(const bf16x8*)&As[cur][(wm * 64 + i * 16 + lm) * 32 + kq];
        #pragma unroll
        for (int j = 0; j < 4; ++j)
            bfr[j] = *(const bf16x8*)&Bs[cur][(wn * 64 + j * 16 + lm) * 32 + kq];
        #pragma unroll
        for (int i = 0; i < 4; ++i)
            #pragma unroll
            for (int j = 0; j < 4; ++j)
                acc[i][j] = __builtin_amdgcn_mfma_f32_16x16x32_bf16(af[i], bfr[j], acc[i][j], 0, 0, 0);
        __asm__ volatile("" ::: "memory");
        cur = (cur == 2) ? 0 : cur + 1;
    }

    // C/D layout: col = lane&15, row = (lane>>4)*4 + reg
    #pragma unroll
    for (int i = 0; i < 4; ++i){
        const int m = m0 + wm * 64 + i * 16 + (lane >> 4) * 4;
        #pragma unroll
        for (int j = 0; j < 4; ++j){
            const int n = n0 + wn * 64 + j * 16 + lm;
            if (n < N){
                const float bb = bias ? bias[n] : 0.f;
                #pragma unroll
                for (int r = 0; r < 4; ++r){
                    float v = acc[i][j][r] * alpha + bb;
                    if ((causal & 1) && n > m + r) v = -1e9f;
                    if constexpr (sizeof(TC) == 2)
                        C[(size_t)(m + r) * ldc + n] = (TC)f2b(v);
                    else
                        C[(size_t)(m + r) * ldc + n] = (TC)v;
                }
            }
        }
    }
}

// Generic launcher (same interface as before).
// causal bit0: compact triangular tile decode (index = bm), mask in epilogue.
// causal bit1: K = min(K, m0+128).  causal bit2: z-first grid.
template<typename TC>
__global__ __launch_bounds__(256) void mfma_gemm_bt(
    const unsigned short* __restrict__ A, const unsigned short* __restrict__ B,
    const float* __restrict__ bias, TC* __restrict__ C,
    int M, int N, int K, int lda, int ldb, int ldc,
    int zdiv, long sA_hi, long sA_lo, long sB_hi, long sB_lo, long sC_hi, long sC_lo,
    float alpha, int causal)
{
    int z, bm, bn;
    if (causal & 4){ z = blockIdx.x; bm = blockIdx.y; bn = blockIdx.z; }
    else           { z = blockIdx.z; bm = blockIdx.y; bn = blockIdx.x; }
    int m0, n0;
    if (causal & 1){
        int i = bm;
        int mt = (int)((sqrtf(8.f * i + 1.f) - 1.f) * 0.5f);
        while ((mt + 1) * (mt + 2) / 2 <= i) ++mt;
        while (mt * (mt + 1) / 2 > i) --mt;
        n0 = (i - mt * (mt + 1) / 2) * 128;
        m0 = mt * 128;
    } else { m0 = bm * 128; n0 = bn * 128; }
    if (causal & 2) K = min(K, m0 + 128);

    __shared__ unsigned short As[3][4096];
    __shared__ unsigned short Bs[3][4096];
    const int zh = z / zdiv, zl = z % zdiv;
    A += (size_t)zh * sA_hi + (size_t)zl * sA_lo;
    B += (size_t)zh * sB_hi + (size_t)zl * sB_lo;
    C += (size_t)zh * sC_hi + (size_t)zl * sC_lo;

    gemm_body<TC>(As, Bs, A, B, bias, C, N, K, lda, ldb, ldc, m0, n0, alpha, causal);
}

// Merged vhT + kh launch (both are w_x[h](128x512) x kvn[b]^T(512x1024) shapes,
// previously two sequential 256-block launches = 1 block/CU each with full
// tails). Parity-interleaved 512 blocks -> CUs host one of each.
// p=0 (vhT): C[d][t] = w_v[h] @ kvn[b]^T   (M=128, N=1024, ldc=1024)
// p=1 (kh):  C[t][d] = kvn[b] @ w_k[h]^T   (M=1024, N=128, ldc=192)
__global__ __launch_bounds__(256) void mfma_gemm_vk(
    const unsigned short* __restrict__ kvuw,  // [4096][512]: w_k rows 0..2047, w_v 2048..4095
    const unsigned short* __restrict__ kcat,  // [2048][576] (kvn rows, ldb=576)
    unsigned short* __restrict__ vhT,         // [2][16][128][1024]
    unsigned short* __restrict__ khcat)       // [32][1024][192]
{
    __shared__ unsigned short As[3][4096];
    __shared__ unsigned short Bs[3][4096];
    const int p = blockIdx.x & 1, z = blockIdx.x >> 1, y = blockIdx.y;
    const int b = z >> 4, h = z & 15;
    if (p == 0){
        const unsigned short* A = kvuw + 1048576 + (size_t)h * 65536;  // w_v[h]
        const unsigned short* B = kcat + (size_t)b * 589824;
        unsigned short* C = vhT + (size_t)b * 2097152 + (size_t)h * 131072;
        gemm_body<unsigned short>(As, Bs, A, B, nullptr, C,
                                  1024, 512, 512, 576, 1024, 0, y * 128, 1.0f, 0);
    } else {
        const unsigned short* A = kcat + (size_t)b * 589824;
        const unsigned short* B = kvuw + (size_t)h * 65536;            // w_k[h]
        unsigned short* C = khcat + (size_t)b * 3145728 + (size_t)h * 196608;
        gemm_body<unsigned short>(As, Bs, A, B, nullptr, C,
                                  128, 512, 576, 512, 192, y * 128, 0, 1.0f, 0);
    }
}

// Fused causal attention v6 (measured best: 40.6us): score dim = 192.
// One (b,h,64-row q-tile) per block; 512 blocks, 1-D grid.
// Balanced block->(z,mt) mapping: nkt sequence where blocks at distance
// 1, 8, 256 have complementary work (sums == 9). Chunk0 cross-tile prefetch
// (Ks[2]); counted vmcnt (24/20/16); lgkm-only barriers; V drained at PV;
// s_setprio around MFMA clusters.
__global__ __launch_bounds__(256) void flash_attn(
    const unsigned short* __restrict__ qu,    // [2048][3072], q_rot slices roped
    const unsigned short* __restrict__ khcat, // [32][1024][192] = [kh | k_rot]
    const unsigned short* __restrict__ vhT,   // [2][16][128][1024]
    unsigned short* __restrict__ ctx)         // [2048][2048]
{
    // base pattern (period 16): 8,1,7,2,6,3,5,4, 1,8,2,7,3,6,4,5
    // second 256 blocks: complement (9-v). Distances 1,8,256 all sum to 9.
    const int t = blockIdx.x;
    const int k15 = t & 15, kl = k15 & 7;
    int v = (kl & 1) ? (1 + (kl >> 1)) : (8 - (kl >> 1));
    if (k15 & 8) v = 9 - v;
    if (t & 256) v = 9 - v;
    const int o = ((t >> 4) & 15) * 2 + (k15 >> 3) + ((t >> 8) << 5);  // 0..63
    const int mt = 2 * v - 2 + (o & 1);       // 0..15
    const int z  = o >> 1;                    // 0..31
    const int b = z >> 4, h = z & 15;
    const int m0 = mt * 64;
    const int nkt = v;                        // == (mt>>1)+1

    __shared__ char smem[74240];
    unsigned short (*Qs)[4096] = (unsigned short (*)[4096])smem;            // 3 x 64x64 (Q resident)
    unsigned short (*Ks)[8192] = (unsigned short (*)[8192])(smem + 24576);  // 3 x 128x64
    unsigned short* Ps = (unsigned short*)(smem + 24576);                   // 64x136, aliases Ks[0..1]
    float* lrow = (float*)(smem + 73728);                                   // [2][64]

    const unsigned short* kB = khcat + (size_t)z * 196608;
    const unsigned short* vB = vhT + (size_t)z * 131072;

    const int tid = threadIdx.x, w = tid >> 6, lane = tid & 63;
    const int wm = w >> 1, wn = w & 1;
    const int lm = lane & 15, g = lane >> 4;
    const int kq = g * 8;
    const int rs7 = lm & 7;                   // row&7 for swizzled reads

    if (tid < 128) lrow[tid] = 0.f;

    const int srow8 = lane >> 3;              // 0..7
    const int soff8 = ((lane & 7) ^ (lane >> 3)) * 8;  // swizzled global chunk
    const unsigned short* gQ = qu + (size_t)(b * 1024 + m0 + w * 16 + srow8) * 3072
                               + h * 192 + soff8;

    // Q resident: 192 k = 3 chunk-buffers, staged once (6 loads/wave).
    #pragma unroll
    for (int c = 0; c < 3; ++c){
        gl2lds16(gQ + c * 64,            &Qs[c][w * 1024]);
        gl2lds16(gQ + c * 64 + 8 * 3072, &Qs[c][w * 1024 + 512]);
    }

    // K chunks with FIXED buffer roles: chunk0 -> Ks[2] (prefetched one
    // kv-tile ahead), chunk1 -> Ks[0], chunk2 -> Ks[1].
    auto stageK = [&](int buf, int kt, int c){
        const unsigned short* gK = kB + (size_t)(kt * 128 + w * 32 + srow8) * 192
                                   + c * 64 + soff8;
        gl2lds16(gK,            &Ks[buf][w * 2048]);
        gl2lds16(gK + 8 * 192,  &Ks[buf][w * 2048 + 512]);
        gl2lds16(gK + 16 * 192, &Ks[buf][w * 2048 + 1024]);
        gl2lds16(gK + 24 * 192, &Ks[buf][w * 2048 + 1536]);
    };
    stageK(2, 0, 0);                          // chunk0 of tile 0

    f32x4 Oacc[2][4] = {};
    const float scl = 0.07216878364870322f;   // 1/sqrt(192)

    for (int kt = 0; kt < nkt; ++kt){
        stageK(0, kt, 1);                     // chunk1 -> buf0 (Ps dead now)
        stageK(1, kt, 2);                     // chunk2 -> buf1
        __asm__ volatile("" ::: "memory");    // pin V loads AFTER K stages
        bf16x8 vfr[4][4];
        #pragma unroll
        for (int j = 0; j < 4; ++j)
            #pragma unroll
            for (int kc = 0; kc < 4; ++kc)
                vfr[j][kc] = *(const bf16x8*)(vB + (size_t)(wn * 64 + j * 16 + lm) * 1024
                                              + kt * 128 + kc * 32 + kq);
        __asm__ volatile("" ::: "memory");

        // vm queue (oldest first), steady state: [pf chunk0(4)] (kt=0: Q(6)+
        // chunk0(4)), chunk1(4), chunk2(4), V(16) = 28 (34 on kt=0).
        f32x4 S[2][4] = {};
        #pragma unroll
        for (int c = 0; c < 3; ++c){
            if      (c == 0) __builtin_amdgcn_s_waitcnt(0x4F78);  // vmcnt(24): chunk0 (+Q) in
            else if (c == 1) __builtin_amdgcn_s_waitcnt(0x4F74);  // vmcnt(20): chunk1 in
            else             __builtin_amdgcn_s_waitcnt(0x4F70);  // vmcnt(16): chunk2 in, V in flight
            __builtin_amdgcn_s_barrier();
            __asm__ volatile("" ::: "memory");
            const int bufc = (c == 0) ? 2 : (c - 1);
            bf16x8 af[2][2], bfr[4][2];
            #pragma unroll
            for (int i = 0; i < 2; ++i)
                #pragma unroll
                for (int kk = 0; kk < 2; ++kk)
                    af[i][kk] = *(const bf16x8*)&Qs[c][(wm * 32 + i * 16 + lm) * 64
                                                       + (((kk * 4 + g) ^ rs7) * 8)];
            #pragma unroll
            for (int j = 0; j < 4; ++j)
                #pragma unroll
                for (int kk = 0; kk < 2; ++kk)
                    bfr[j][kk] = *(const bf16x8*)&Ks[bufc][(wn * 64 + j * 16 + lm) * 64
                                                           + (((kk * 4 + g) ^ rs7) * 8)];
            __builtin_amdgcn_s_setprio(1);
            #pragma unroll
            for (int kk = 0; kk < 2; ++kk)
                #pragma unroll
                for (int i = 0; i < 2; ++i)
                    #pragma unroll
                    for (int j = 0; j < 4; ++j)
                        S[i][j] = __builtin_amdgcn_mfma_f32_16x16x32_bf16(af[i][kk], bfr[j][kk], S[i][j], 0, 0, 0);
            __builtin_amdgcn_s_setprio(0);
            __asm__ volatile("" ::: "memory");
        }
        // all QK reads of Ks done -> Ps (alias) writable. lgkm-only barrier:
        // keep the vm queue (V + upcoming prefetch) alive across it.
        __builtin_amdgcn_s_waitcnt(0xC07F);   // lgkmcnt(0), vmcnt untouched
        __builtin_amdgcn_s_barrier();
        __asm__ volatile("" ::: "memory");
        if (kt + 1 < nkt) stageK(2, kt + 1, 0);   // prefetch next chunk0 -> buf2

        // softmax numerator (global-index causal mask on the diagonal tile);
        // row sums; P -> LDS (aliased on Ks[0..1]) in [m][k] layout.
        const bool diag = (kt == (mt >> 1));
        #pragma unroll
        for (int i = 0; i < 2; ++i){
            float rs[4] = {0.f, 0.f, 0.f, 0.f};
            #pragma unroll
            for (int j = 0; j < 4; ++j){
                const int nloc = wn * 64 + j * 16 + lm;
                #pragma unroll
                for (int r = 0; r < 4; ++r){
                    const int mloc = wm * 32 + i * 16 + g * 4 + r;
                    float p = __expf(S[i][j][r] * scl);
                    if (diag && (kt * 128 + nloc) > (m0 + mloc)) p = 0.f;
                    rs[r] += p;
                    Ps[mloc * 136 + nloc] = f2b(p);
                }
            }
            #pragma unroll
            for (int r = 0; r < 4; ++r){
                rs[r] += __shfl_xor(rs[r], 1, 64);
                rs[r] += __shfl_xor(rs[r], 2, 64);
                rs[r] += __shfl_xor(rs[r], 4, 64);
                rs[r] += __shfl_xor(rs[r], 8, 64);
            }
            if (lm == 0){
                #pragma unroll
                for (int r = 0; r < 4; ++r)
                    lrow[wn * 64 + wm * 32 + i * 16 + g * 4 + r] += rs[r];
            }
        }
        __asm__ volatile("" ::: "memory");
        __builtin_amdgcn_s_waitcnt(0xC07F);   // Ps + lrow visible
        __builtin_amdgcn_s_barrier();
        __asm__ volatile("" ::: "memory");

        // O += P @ V^T  (A = Ps rows, B = vfr registers). V drained here
        // (in-order vm retirement; prefetched chunk0 may stay in flight).
        if (kt + 1 < nkt) __builtin_amdgcn_s_waitcnt(0xF74);  // vmcnt(4)
        else              __builtin_amdgcn_s_waitcnt(0xF70);  // vmcnt(0)
        #pragma unroll
        for (int kc = 0; kc < 4; ++kc){
            bf16x8 pa[2];
            #pragma unroll
            for (int i = 0; i < 2; ++i)
                pa[i] = *(const bf16x8*)&Ps[(wm * 32 + i * 16 + lm) * 136 + kc * 32 + kq];
            __builtin_amdgcn_s_setprio(1);
            #pragma unroll
            for (int i = 0; i < 2; ++i)
                #pragma unroll
                for (int j = 0; j < 4; ++j)
                    Oacc[i][j] = __builtin_amdgcn_mfma_f32_16x16x32_bf16(pa[i], vfr[j][kc], Oacc[i][j], 0, 0, 0);
            __builtin_amdgcn_s_setprio(0);
        }
        __asm__ volatile("" ::: "memory");
        __builtin_amdgcn_s_waitcnt(0xC07F);   // Ps reads done -> next kt restages buf0/1
        __builtin_amdgcn_s_barrier();
        __asm__ volatile("" ::: "memory");
    }

    // normalize and store: ctx[(b*1024+m0+row)][h*128 + col]
    unsigned short* cBase = ctx + ((size_t)(b * 1024 + m0)) * 2048 + h * 128;
    #pragma unroll
    for (int i = 0; i < 2; ++i){
        #pragma unroll
        for (int r = 0; r < 4; ++r){
            const int row = wm * 32 + i * 16 + g * 4 + r;
            const float inv = 1.f / (lrow[row] + lrow[64 + row]);
            #pragma unroll
            for (int j = 0; j < 4; ++j){
                const int col = wn * 64 + j * 16 + lm;
                cBase[(size_t)row * 2048 + col] = f2b(Oacc[i][j][r] * inv);
            }
        }
    }
}

// One launch casting all six f32 weight/activation blobs to bf16.
__global__ __launch_bounds__(256) void cast_all(
    const float* __restrict__ s0, unsigned short* __restrict__ d0,   // x      4194304
    const float* __restrict__ s1, unsigned short* __restrict__ d1,   // q_down 1572864
    const float* __restrict__ s2, unsigned short* __restrict__ d2,   // q_up   2359296
    const float* __restrict__ s3, unsigned short* __restrict__ d3,   // kv_down1179648
    const float* __restrict__ s4, unsigned short* __restrict__ d4,   // kv_up  2097152
    const float* __restrict__ s5, unsigned short* __restrict__ d5)   // out_w  4194304
{
    long i = (long)(blockIdx.x * 256 + threadIdx.x) * 4;
    const float* s; unsigned short* d; long off;
    if      (i <  4194304L){ s = s0; d = d0; off = i; }
    else if (i <  5767168L){ s = s1; d = d1; off = i -  4194304L; }
    else if (i <  8126464L){ s = s2; d = d2; off = i -  5767168L; }
    else if (i <  9306112L){ s = s3; d = d3; off = i -  8126464L; }
    else if (i < 11403264L){ s = s4; d = d4; off = i -  9306112L; }
    else                   { s = s5; d = d5; off = i - 11403264L; }
    float4 v = *(const float4*)(s + off);
    *(ushort4*)(d + off) = make_ushort4(f2b(v.x), f2b(v.y), f2b(v.z), f2b(v.w));
}

// Fused down-proj epilogue. p = [4][2048][1344] bf16 split-K partials.
__global__ __launch_bounds__(256) void fused_down_post(
    const unsigned short* __restrict__ p,
    const float* __restrict__ q_down_b, const float* __restrict__ kv_down_b,
    const float* __restrict__ q_norm_s, const float* __restrict__ kv_norm_s,
    unsigned short* __restrict__ qn, unsigned short* __restrict__ kcat)
{
    __shared__ float row[1344];
    __shared__ float red[4];
    const int t = blockIdx.x, tid = threadIdx.x;
    const long S = 2752512L; // 2048*1344
    const unsigned short* b0 = p + (size_t)t * 1344;
    for (int c = tid; c < 1344; c += 256){
        float v = b2f(b0[c]) + b2f(b0[c + S]) + b2f(b0[c + 2*S]) + b2f(b0[c + 3*S]);
        v += (c < 768) ? q_down_b[c] : kv_down_b[c - 768];
        row[c] = v;
    }
    __syncthreads();
    const int lane = tid & 63, w = tid >> 6;
    float ss = 0.f;
    for (int c = tid; c < 768; c += 256){ float v = row[c]; ss += v * v; }
    #pragma unroll
    for (int o = 32; o > 0; o >>= 1) ss += __shfl_xor(ss, o, 64);
    if (lane == 0) red[w] = ss;
    __syncthreads();
    const float inv1 = rsqrtf((red[0]+red[1]+red[2]+red[3]) / 768.f + 1e-6f);
    __syncthreads();
    ss = 0.f;
    for (int c = tid; c < 512; c += 256){ float v = row[768 + c]; ss += v * v; }
    #pragma unroll
    for (int o = 32; o > 0; o >>= 1) ss += __shfl_xor(ss, o, 64);
    if (lane == 0) red[w] = ss;
    __syncthreads();
    const float inv2 = rsqrtf((red[0]+red[1]+red[2]+red[3]) / 512.f + 1e-6f);
    for (int c = tid; c < 768; c += 256)
        qn[(size_t)t * 768 + c] = f2b(q_norm_s[c] * row[c] * inv1);
    for (int c = tid; c < 512; c += 256)
        kcat[(size_t)t * 576 + c] = f2b(kv_norm_s[c] * row[768 + c] * inv2);
    if (tid < 64){
        const int d = tid, s = t & 1023;
        float x  = row[1280 + d];
        float xp = (d < 32) ? -row[1280 + d + 32] : row[1280 + d - 32];
        float ang = (float)s * powf(10000.f, -(float)(2 * (d & 31)) / 64.f);
        kcat[(size_t)t * 576 + 512 + d] = f2b(x * cosf(ang) + xp * sinf(ang));
    }
}

// Combined: (1) pairwise in-place RoPE on qu's q_rot slices (thread owns the
// (d, d+32) pair -> no race); (2) broadcast roped k_rot into khcat cols 128..192.
__global__ __launch_bounds__(256) void rope_q_krot(
    unsigned short* __restrict__ qu,          // [2048][3072]
    const unsigned short* __restrict__ kcat,  // [2048][576]
    unsigned short* __restrict__ khcat)       // [32][1024][192]
{
    long idx = (long)blockIdx.x * 256 + threadIdx.x;
    if (idx < 1048576L){
        const int d   = idx & 31;
        const int h   = (idx >> 5) & 15;
        const int tok = idx >> 9;
        const int s   = tok & 1023;
        unsigned short* base = qu + (size_t)tok * 3072 + h * 192 + 128;
        float x1 = b2f(base[d]), x2 = b2f(base[d + 32]);
        float ang = (float)s * powf(10000.f, -(float)d / 32.f);
        float c = cosf(ang), sn = sinf(ang);
        base[d]      = f2b(x1 * c - x2 * sn);
        base[d + 32] = f2b(x2 * c + x1 * sn);
    } else {
        idx -= 1048576L;
        const int d   = idx & 63;
        const int h   = (idx >> 6) & 15;
        const int tok = (int)(idx >> 10);
        const int bb  = tok >> 10, s = tok & 1023;
        khcat[((size_t)(bb * 16 + h) * 1024 + s) * 192 + 128 + d] =
            kcat[(size_t)tok * 576 + 512 + d];
    }
}

extern "C" void kernel_launch(void* const* d_in, const int* in_sizes, int n_in,
                              void* d_out, int out_size, void* d_ws, size_t ws_size,
                              hipStream_t stream)
{
    const float* x         = (const float*)d_in[0];
    const float* q_down_w  = (const float*)d_in[3];
    const float* q_down_b  = (const float*)d_in[4];
    const float* q_norm_s  = (const float*)d_in[5];
    const float* q_up_w    = (const float*)d_in[6];
    const float* q_up_b    = (const float*)d_in[7];
    const float* kv_down_w = (const float*)d_in[8];
    const float* kv_down_b = (const float*)d_in[9];
    const float* kv_norm_s = (const float*)d_in[10];
    const float* kv_up_w   = (const float*)d_in[11];
    const float* out_w     = (const float*)d_in[12];
    const float* out_b     = (const float*)d_in[13];
    float* out = (float*)d_out;

    // Workspace layout (bytes), peak 100,925,440:
    char* ws = (char*)d_ws;
    unsigned short* kvuw  = (unsigned short*)(ws + 0);           // [4096][512] (w_k rows 0..2047, w_v 2048..4095)
    unsigned short* outw  = (unsigned short*)(ws + 4194304);     // [2048][2048]
    unsigned short* kcat  = (unsigned short*)(ws + 12582912);    // [2048][576]
    unsigned short* vhT   = (unsigned short*)(ws + 14942208);    // [2][16][128][1024]
    unsigned short* khcat = (unsigned short*)(ws + 23330816);    // [32][1024][192]
    unsigned short* ctx   = (unsigned short*)(ws + 35913728);    // [2048][2048] bf16
    unsigned short* qu    = (unsigned short*)(ws + 44302336);    // [2048][3072] (live through flash)
    unsigned short* qn    = (unsigned short*)(ws + 56885248);    // [2048][768]
    unsigned short* p_qkv = (unsigned short*)(ws + 60030976);    // [4][2048][1344] bf16 (dead after fdp)
    unsigned short* xb    = (unsigned short*)(ws + 82051072);    // [2048][2048]
    unsigned short* qkdw  = (unsigned short*)(ws + 90439680);    // [1408][2048] concat down-proj w
    unsigned short* quw   = (unsigned short*)(ws + 96206848);    // [3072][768]

    dim3 blk(256);

    // casts: q_down -> qkdw rows 0..767, kv_down -> qkdw rows 768..1343
    cast_all<<<15232, blk, 0, stream>>>(x, xb, q_down_w, qkdw, q_up_w, quw,
                                        kv_down_w, qkdw + 1572864, kv_up_w, kvuw, out_w, outw);

    // k1 (split-K x4, bf16 partials): p_qkv[s] = x[:, s*512:] @ qkdw[:, s*512:]^T
    mfma_gemm_bt<unsigned short><<<dim3(11, 16, 4), blk, 0, stream>>>(
        xb, qkdw, nullptr, p_qkv, 2048, 1344, 512, 2048, 2048, 1344,
        4, 0L, 512L, 0L, 512L, 0L, 2752512L, 1.0f, 0);
    // fused: partial-sum + biases + q-rmsnorm -> qn, kv-rmsnorm/rope -> kcat
    fused_down_post<<<2048, blk, 0, stream>>>(p_qkv, q_down_b, kv_down_b,
                                              q_norm_s, kv_norm_s, qn, kcat);
    // k3: qu = bf16(qn @ q_up_w^T + b)  [2048,3072] K=768
    mfma_gemm_bt<unsigned short><<<dim3(24, 16, 1), blk, 0, stream>>>(
        qn, quw, q_up_b, qu, 2048, 3072, 768, 768, 768, 3072,
        1, 0, 0, 0, 0, 0, 0, 1.0f, 0);
    // merged vhT + kh: 512 parity-interleaved blocks (was 2x256-block launches)
    mfma_gemm_vk<<<dim3(64, 8, 1), blk, 0, stream>>>(kvuw, kcat, vhT, khcat);
    // rope q (in-place on qu) + broadcast roped k_rot into khcat cols 128..192
    rope_q_krot<<<12288, blk, 0, stream>>>(qu, kcat, khcat);
    // fused attention v6 (measured best): balanced 512-block grid
    flash_attn<<<dim3(512), blk, 0, stream>>>(qu, khcat, vhT, ctx);
    // k11 single-pass: out = ctx @ outw^T + out_b (f32 direct; no split-K,
    // no partial round-trip, no reduce_out)
    mfma_gemm_bt<float><<<dim3(16, 16, 1), blk, 0, stream>>>(
        ctx, outw, out_b, out, 2048, 2048, 2048, 2048, 2048, 2048,
        1, 0L, 0L, 0L, 0L, 0L, 0L, 1.0f, 0);
}

// Round 6
// 285.165 us; speedup vs baseline: 1.1009x; 1.0290x over previous
//
#include <hip/hip_runtime.h>
#include <stdint.h>
#include <stddef.h>

// DIM=2048, H=16, Q_RANK=768, KV_RANK=512, QK_STATIC=128, QK_ROT=64,
// QK_TOTAL=192, V_DIM=128, BS=2, SEQ=1024, NTOK=2048.
// Score contraction absorbed on the K side: kh[b,h] = kvn @ W_k[h]^T (128-dim),
// so scores = [q_static | q_rot] . [kh | k_rot] over 192 dims (vs 576).

typedef __attribute__((ext_vector_type(8))) short bf16x8;
typedef __attribute__((ext_vector_type(4))) float f32x4;

__device__ inline float b2f(unsigned short v){
    union { unsigned u; float f; } x; x.u = ((unsigned)v) << 16; return x.f;
}
__device__ inline unsigned short f2b(float f){
    union { float f; unsigned u; } x; x.f = f;
    unsigned r = x.u + 0x7fffu + ((x.u >> 16) & 1u);
    return (unsigned short)(r >> 16);
}

// async global->LDS, 16B per lane. LDS dest = wave-uniform base + lane*16.
__device__ __forceinline__ void gl2lds16(const unsigned short* g, unsigned short* l){
    __builtin_amdgcn_global_load_lds(
        (__attribute__((address_space(1))) void*)const_cast<unsigned short*>(g),
        (__attribute__((address_space(3))) void*)l,
        16, 0, 0);
}

// Shared GEMM body: C[M,N](+=bias) = alpha*(A @ B^T), bf16 in, fp32 acc.
// 128x128 tile, BK=32, 4 waves 2x2, 16x16x32 MFMA, 3-deep global_load_lds
// pipeline (vmcnt(4) waits, raw s_barrier, no full drain). LDS bank swizzle:
// stage global chunk (lane&3)^((lane>>3)&3); reads use chunk g^((row>>1)&3).
// causal bit0: -1e9 above diagonal in epilogue.
template<typename TC>
static __device__ __forceinline__ void gemm_body(
    unsigned short (*As)[4096], unsigned short (*Bs)[4096],
    const unsigned short* A, const unsigned short* B,
    const float* bias, TC* C,
    int N, int K, int lda, int ldb, int ldc,
    int m0, int n0, float alpha, int causal)
{
    const int tid = threadIdx.x, w = tid >> 6, lane = tid & 63;
    const int wm = w >> 1, wn = w & 1;

    const int srow = w * 32 + (lane >> 2);
    const int schunk = ((lane & 3) ^ ((lane >> 3) & 3)) * 8;   // row-bit-1/2 swizzle
    const unsigned short* gA = A + (size_t)(m0 + srow) * lda + schunk;
    const unsigned short* gB = B + (size_t)(n0 + srow) * ldb + schunk;

    const int ktiles = K >> 5;
    auto stage = [&](int buf, int kt){
        const int k0 = kt << 5;
        gl2lds16(gA + k0,            &As[buf][w * 1024]);
        gl2lds16(gA + k0 + 16 * lda, &As[buf][w * 1024 + 512]);
        gl2lds16(gB + k0,            &Bs[buf][w * 1024]);
        gl2lds16(gB + k0 + 16 * ldb, &Bs[buf][w * 1024 + 512]);
    };
    stage(0, 0);
    if (ktiles > 1) stage(1, 1);

    f32x4 acc[4][4] = {};
    const int lm = lane & 15;
    const int kq = (((lane >> 4) ^ (lm >> 1)) & 3) * 8;        // matches stage swizzle

    int cur = 0;
    for (int kt = 0; kt < ktiles; ++kt){
        if (kt + 1 < ktiles) __builtin_amdgcn_s_waitcnt(0xF74);
        else                 __builtin_amdgcn_s_waitcnt(0xF70);
        __builtin_amdgcn_s_barrier();
        __asm__ volatile("" ::: "memory");
        if (kt + 2 < ktiles) stage(cur >= 1 ? cur - 1 : 2, kt + 2);
        bf16x8 af[4], bfr[4];
        #pragma unroll
        for (int i = 0; i < 4; ++i)
            af[i] = *(const bf16x8*)&As[cur][(wm * 64 + i * 16 + lm) * 32 + kq];
        #pragma unroll
        for (int j = 0; j < 4; ++j)
            bfr[j] = *(const bf16x8*)&Bs[cur][(wn * 64 + j * 16 + lm) * 32 + kq];
        #pragma unroll
        for (int i = 0; i < 4; ++i)
            #pragma unroll
            for (int j = 0; j < 4; ++j)
                acc[i][j] = __builtin_amdgcn_mfma_f32_16x16x32_bf16(af[i], bfr[j], acc[i][j], 0, 0, 0);
        __asm__ volatile("" ::: "memory");
        cur = (cur == 2) ? 0 : cur + 1;
    }

    // C/D layout: col = lane&15, row = (lane>>4)*4 + reg
    #pragma unroll
    for (int i = 0; i < 4; ++i){
        const int m = m0 + wm * 64 + i * 16 + (lane >> 4) * 4;
        #pragma unroll
        for (int j = 0; j < 4; ++j){
            const int n = n0 + wn * 64 + j * 16 + lm;
            if (n < N){
                const float bb = bias ? bias[n] : 0.f;
                #pragma unroll
                for (int r = 0; r < 4; ++r){
                    float v = acc[i][j][r] * alpha + bb;
                    if ((causal & 1) && n > m + r) v = -1e9f;
                    if constexpr (sizeof(TC) == 2)
                        C[(size_t)(m + r) * ldc + n] = (TC)f2b(v);
                    else
                        C[(size_t)(m + r) * ldc + n] = (TC)v;
                }
            }
        }
    }
}

// Generic launcher (same interface as before).
// causal bit0: compact triangular tile decode (index = bm), mask in epilogue.
// causal bit1: K = min(K, m0+128).  causal bit2: z-first grid.
template<typename TC>
__global__ __launch_bounds__(256) void mfma_gemm_bt(
    const unsigned short* __restrict__ A, const unsigned short* __restrict__ B,
    const float* __restrict__ bias, TC* __restrict__ C,
    int M, int N, int K, int lda, int ldb, int ldc,
    int zdiv, long sA_hi, long sA_lo, long sB_hi, long sB_lo, long sC_hi, long sC_lo,
    float alpha, int causal)
{
    int z, bm, bn;
    if (causal & 4){ z = blockIdx.x; bm = blockIdx.y; bn = blockIdx.z; }
    else           { z = blockIdx.z; bm = blockIdx.y; bn = blockIdx.x; }
    int m0, n0;
    if (causal & 1){
        int i = bm;
        int mt = (int)((sqrtf(8.f * i + 1.f) - 1.f) * 0.5f);
        while ((mt + 1) * (mt + 2) / 2 <= i) ++mt;
        while (mt * (mt + 1) / 2 > i) --mt;
        n0 = (i - mt * (mt + 1) / 2) * 128;
        m0 = mt * 128;
    } else { m0 = bm * 128; n0 = bn * 128; }
    if (causal & 2) K = min(K, m0 + 128);

    __shared__ unsigned short As[3][4096];
    __shared__ unsigned short Bs[3][4096];
    const int zh = z / zdiv, zl = z % zdiv;
    A += (size_t)zh * sA_hi + (size_t)zl * sA_lo;
    B += (size_t)zh * sB_hi + (size_t)zl * sB_lo;
    C += (size_t)zh * sC_hi + (size_t)zl * sC_lo;

    gemm_body<TC>(As, Bs, A, B, bias, C, N, K, lda, ldb, ldc, m0, n0, alpha, causal);
}

// Merged vhT + kh launch (both are w_x[h](128x512) x kvn[b]^T(512x1024) shapes,
// previously two sequential 256-block launches = 1 block/CU each with full
// tails). Parity-interleaved 512 blocks -> CUs host one of each.
// p=0 (vhT): C[d][t] = w_v[h] @ kvn[b]^T   (M=128, N=1024, ldc=1024)
// p=1 (kh):  C[t][d] = kvn[b] @ w_k[h]^T   (M=1024, N=128, ldc=192)
__global__ __launch_bounds__(256) void mfma_gemm_vk(
    const unsigned short* __restrict__ kvuw,  // [4096][512]: w_k rows 0..2047, w_v 2048..4095
    const unsigned short* __restrict__ kcat,  // [2048][576] (kvn rows, ldb=576)
    unsigned short* __restrict__ vhT,         // [2][16][128][1024]
    unsigned short* __restrict__ khcat)       // [32][1024][192]
{
    __shared__ unsigned short As[3][4096];
    __shared__ unsigned short Bs[3][4096];
    const int p = blockIdx.x & 1, z = blockIdx.x >> 1, y = blockIdx.y;
    const int b = z >> 4, h = z & 15;
    if (p == 0){
        const unsigned short* A = kvuw + 1048576 + (size_t)h * 65536;  // w_v[h]
        const unsigned short* B = kcat + (size_t)b * 589824;
        unsigned short* C = vhT + (size_t)b * 2097152 + (size_t)h * 131072;
        gemm_body<unsigned short>(As, Bs, A, B, nullptr, C,
                                  1024, 512, 512, 576, 1024, 0, y * 128, 1.0f, 0);
    } else {
        const unsigned short* A = kcat + (size_t)b * 589824;
        const unsigned short* B = kvuw + (size_t)h * 65536;            // w_k[h]
        unsigned short* C = khcat + (size_t)b * 3145728 + (size_t)h * 196608;
        gemm_body<unsigned short>(As, Bs, A, B, nullptr, C,
                                  128, 512, 576, 512, 192, y * 128, 0, 1.0f, 0);
    }
}

// Fused causal attention v9: v6 body (proven 40.6us) with a mapping that has
// BOTH v6's work-complementarity AND v5's XCD locality:
//   r = t&7 -> z%8 == t%8 (same-z blocks on the same XCD under n%8 dispatch;
//   4 z's per XCD = 2.6MB K/V, fits the 4MB XCD L2 -> v5-validated FETCH ~16-22MB)
//   t and t+256 map to the SAME z with nkt(t)+nkt(t+256) == 9 (v6's balance:
//   the backfill block a CU picks up complements its first block's work).
//   mt_seq over u=q>>2: [15,13,11,9,7,5,3,1 | 0,2,4,6,8,10,12,14].
// Chunk0 cross-tile prefetch (Ks[2]); counted vmcnt (24/20/16); lgkm-only
// barriers; V drained at PV; s_setprio around MFMA clusters.
__global__ __launch_bounds__(256) void flash_attn(
    const unsigned short* __restrict__ qu,    // [2048][3072], q_rot slices roped
    const unsigned short* __restrict__ khcat, // [32][1024][192] = [kh | k_rot]
    const unsigned short* __restrict__ vhT,   // [2][16][128][1024]
    unsigned short* __restrict__ ctx)         // [2048][2048]
{
    const int t = blockIdx.x;
    const int r = t & 7, q = t >> 3;
    const int z = r + 8 * (q & 3);            // z%8 == t%8 -> XCD-local K/V
    const int u = q >> 2;                     // 0..15 (u>=8 <=> t>=256)
    const int mt = (u < 8) ? (15 - 2 * u) : (2 * (u - 8));
    const int b = z >> 4, h = z & 15;
    const int m0 = mt * 64;
    const int nkt = (mt >> 1) + 1;

    __shared__ char smem[74240];
    unsigned short (*Qs)[4096] = (unsigned short (*)[4096])smem;            // 3 x 64x64 (Q resident)
    unsigned short (*Ks)[8192] = (unsigned short (*)[8192])(smem + 24576);  // 3 x 128x64
    unsigned short* Ps = (unsigned short*)(smem + 24576);                   // 64x136, aliases Ks[0..1]
    float* lrow = (float*)(smem + 73728);                                   // [2][64]

    const unsigned short* kB = khcat + (size_t)z * 196608;
    const unsigned short* vB = vhT + (size_t)z * 131072;

    const int tid = threadIdx.x, w = tid >> 6, lane = tid & 63;
    const int wm = w >> 1, wn = w & 1;
    const int lm = lane & 15, g = lane >> 4;
    const int kq = g * 8;
    const int rs7 = lm & 7;                   // row&7 for swizzled reads

    if (tid < 128) lrow[tid] = 0.f;

    const int srow8 = lane >> 3;              // 0..7
    const int soff8 = ((lane & 7) ^ (lane >> 3)) * 8;  // swizzled global chunk
    const unsigned short* gQ = qu + (size_t)(b * 1024 + m0 + w * 16 + srow8) * 3072
                               + h * 192 + soff8;

    // Q resident: 192 k = 3 chunk-buffers, staged once (6 loads/wave).
    #pragma unroll
    for (int c = 0; c < 3; ++c){
        gl2lds16(gQ + c * 64,            &Qs[c][w * 1024]);
        gl2lds16(gQ + c * 64 + 8 * 3072, &Qs[c][w * 1024 + 512]);
    }

    // K chunks with FIXED buffer roles: chunk0 -> Ks[2] (prefetched one
    // kv-tile ahead), chunk1 -> Ks[0], chunk2 -> Ks[1].
    auto stageK = [&](int buf, int kt, int c){
        const unsigned short* gK = kB + (size_t)(kt * 128 + w * 32 + srow8) * 192
                                   + c * 64 + soff8;
        gl2lds16(gK,            &Ks[buf][w * 2048]);
        gl2lds16(gK + 8 * 192,  &Ks[buf][w * 2048 + 512]);
        gl2lds16(gK + 16 * 192, &Ks[buf][w * 2048 + 1024]);
        gl2lds16(gK + 24 * 192, &Ks[buf][w * 2048 + 1536]);
    };
    stageK(2, 0, 0);                          // chunk0 of tile 0

    f32x4 Oacc[2][4] = {};
    const float scl = 0.07216878364870322f;   // 1/sqrt(192)

    for (int kt = 0; kt < nkt; ++kt){
        stageK(0, kt, 1);                     // chunk1 -> buf0 (Ps dead now)
        stageK(1, kt, 2);                     // chunk2 -> buf1
        __asm__ volatile("" ::: "memory");    // pin V loads AFTER K stages
        bf16x8 vfr[4][4];
        #pragma unroll
        for (int j = 0; j < 4; ++j)
            #pragma unroll
            for (int kc = 0; kc < 4; ++kc)
                vfr[j][kc] = *(const bf16x8*)(vB + (size_t)(wn * 64 + j * 16 + lm) * 1024
                                              + kt * 128 + kc * 32 + kq);
        __asm__ volatile("" ::: "memory");

        // vm queue (oldest first), steady state: [pf chunk0(4)] (kt=0: Q(6)+
        // chunk0(4)), chunk1(4), chunk2(4), V(16) = 28 (34 on kt=0).
        f32x4 S[2][4] = {};
        #pragma unroll
        for (int c = 0; c < 3; ++c){
            if      (c == 0) __builtin_amdgcn_s_waitcnt(0x4F78);  // vmcnt(24): chunk0 (+Q) in
            else if (c == 1) __builtin_amdgcn_s_waitcnt(0x4F74);  // vmcnt(20): chunk1 in
            else             __builtin_amdgcn_s_waitcnt(0x4F70);  // vmcnt(16): chunk2 in, V in flight
            __builtin_amdgcn_s_barrier();
            __asm__ volatile("" ::: "memory");
            const int bufc = (c == 0) ? 2 : (c - 1);
            bf16x8 af[2][2], bfr[4][2];
            #pragma unroll
            for (int i = 0; i < 2; ++i)
                #pragma unroll
                for (int kk = 0; kk < 2; ++kk)
                    af[i][kk] = *(const bf16x8*)&Qs[c][(wm * 32 + i * 16 + lm) * 64
                                                       + (((kk * 4 + g) ^ rs7) * 8)];
            #pragma unroll
            for (int j = 0; j < 4; ++j)
                #pragma unroll
                for (int kk = 0; kk < 2; ++kk)
                    bfr[j][kk] = *(const bf16x8*)&Ks[bufc][(wn * 64 + j * 16 + lm) * 64
                                                           + (((kk * 4 + g) ^ rs7) * 8)];
            __builtin_amdgcn_s_setprio(1);
            #pragma unroll
            for (int kk = 0; kk < 2; ++kk)
                #pragma unroll
                for (int i = 0; i < 2; ++i)
                    #pragma unroll
                    for (int j = 0; j < 4; ++j)
                        S[i][j] = __builtin_amdgcn_mfma_f32_16x16x32_bf16(af[i][kk], bfr[j][kk], S[i][j], 0, 0, 0);
            __builtin_amdgcn_s_setprio(0);
            __asm__ volatile("" ::: "memory");
        }
        // all QK reads of Ks done -> Ps (alias) writable. lgkm-only barrier:
        // keep the vm queue (V + upcoming prefetch) alive across it.
        __builtin_amdgcn_s_waitcnt(0xC07F);   // lgkmcnt(0), vmcnt untouched
        __builtin_amdgcn_s_barrier();
        __asm__ volatile("" ::: "memory");
        if (kt + 1 < nkt) stageK(2, kt + 1, 0);   // prefetch next chunk0 -> buf2

        // softmax numerator (global-index causal mask on the diagonal tile);
        // row sums; P -> LDS (aliased on Ks[0..1]) in [m][k] layout.
        const bool diag = (kt == (mt >> 1));
        #pragma unroll
        for (int i = 0; i < 2; ++i){
            float rs[4] = {0.f, 0.f, 0.f, 0.f};
            #pragma unroll
            for (int j = 0; j < 4; ++j){
                const int nloc = wn * 64 + j * 16 + lm;
                #pragma unroll
                for (int r2 = 0; r2 < 4; ++r2){
                    const int mloc = wm * 32 + i * 16 + g * 4 + r2;
                    float p = __expf(S[i][j][r2] * scl);
                    if (diag && (kt * 128 + nloc) > (m0 + mloc)) p = 0.f;
                    rs[r2] += p;
                    Ps[mloc * 136 + nloc] = f2b(p);
                }
            }
            #pragma unroll
            for (int r2 = 0; r2 < 4; ++r2){
                rs[r2] += __shfl_xor(rs[r2], 1, 64);
                rs[r2] += __shfl_xor(rs[r2], 2, 64);
                rs[r2] += __shfl_xor(rs[r2], 4, 64);
                rs[r2] += __shfl_xor(rs[r2], 8, 64);
            }
            if (lm == 0){
                #pragma unroll
                for (int r2 = 0; r2 < 4; ++r2)
                    lrow[wn * 64 + wm * 32 + i * 16 + g * 4 + r2] += rs[r2];
            }
        }
        __asm__ volatile("" ::: "memory");
        __builtin_amdgcn_s_waitcnt(0xC07F);   // Ps + lrow visible
        __builtin_amdgcn_s_barrier();
        __asm__ volatile("" ::: "memory");

        // O += P @ V^T  (A = Ps rows, B = vfr registers). V drained here
        // (in-order vm retirement; prefetched chunk0 may stay in flight).
        if (kt + 1 < nkt) __builtin_amdgcn_s_waitcnt(0xF74);  // vmcnt(4)
        else              __builtin_amdgcn_s_waitcnt(0xF70);  // vmcnt(0)
        #pragma unroll
        for (int kc = 0; kc < 4; ++kc){
            bf16x8 pa[2];
            #pragma unroll
            for (int i = 0; i < 2; ++i)
                pa[i] = *(const bf16x8*)&Ps[(wm * 32 + i * 16 + lm) * 136 + kc * 32 + kq];
            __builtin_amdgcn_s_setprio(1);
            #pragma unroll
            for (int i = 0; i < 2; ++i)
                #pragma unroll
                for (int j = 0; j < 4; ++j)
                    Oacc[i][j] = __builtin_amdgcn_mfma_f32_16x16x32_bf16(pa[i], vfr[j][kc], Oacc[i][j], 0, 0, 0);
            __builtin_amdgcn_s_setprio(0);
        }
        __asm__ volatile("" ::: "memory");
        __builtin_amdgcn_s_waitcnt(0xC07F);   // Ps reads done -> next kt restages buf0/1
        __builtin_amdgcn_s_barrier();
        __asm__ volatile("" ::: "memory");
    }

    // normalize and store: ctx[(b*1024+m0+row)][h*128 + col]
    unsigned short* cBase = ctx + ((size_t)(b * 1024 + m0)) * 2048 + h * 128;
    #pragma unroll
    for (int i = 0; i < 2; ++i){
        #pragma unroll
        for (int r2 = 0; r2 < 4; ++r2){
            const int row = wm * 32 + i * 16 + g * 4 + r2;
            const float inv = 1.f / (lrow[row] + lrow[64 + row]);
            #pragma unroll
            for (int j = 0; j < 4; ++j){
                const int col = wn * 64 + j * 16 + lm;
                cBase[(size_t)row * 2048 + col] = f2b(Oacc[i][j][r2] * inv);
            }
        }
    }
}

// One launch casting all six f32 weight/activation blobs to bf16.
__global__ __launch_bounds__(256) void cast_all(
    const float* __restrict__ s0, unsigned short* __restrict__ d0,   // x      4194304
    const float* __restrict__ s1, unsigned short* __restrict__ d1,   // q_down 1572864
    const float* __restrict__ s2, unsigned short* __restrict__ d2,   // q_up   2359296
    const float* __restrict__ s3, unsigned short* __restrict__ d3,   // kv_down1179648
    const float* __restrict__ s4, unsigned short* __restrict__ d4,   // kv_up  2097152
    const float* __restrict__ s5, unsigned short* __restrict__ d5)   // out_w  4194304
{
    long i = (long)(blockIdx.x * 256 + threadIdx.x) * 4;
    const float* s; unsigned short* d; long off;
    if      (i <  4194304L){ s = s0; d = d0; off = i; }
    else if (i <  5767168L){ s = s1; d = d1; off = i -  4194304L; }
    else if (i <  8126464L){ s = s2; d = d2; off = i -  5767168L; }
    else if (i <  9306112L){ s = s3; d = d3; off = i -  8126464L; }
    else if (i < 11403264L){ s = s4; d = d4; off = i -  9306112L; }
    else                   { s = s5; d = d5; off = i - 11403264L; }
    float4 v = *(const float4*)(s + off);
    *(ushort4*)(d + off) = make_ushort4(f2b(v.x), f2b(v.y), f2b(v.z), f2b(v.w));
}

// Fused down-proj epilogue. p = [4][2048][1344] bf16 split-K partials.
__global__ __launch_bounds__(256) void fused_down_post(
    const unsigned short* __restrict__ p,
    const float* __restrict__ q_down_b, const float* __restrict__ kv_down_b,
    const float* __restrict__ q_norm_s, const float* __restrict__ kv_norm_s,
    unsigned short* __restrict__ qn, unsigned short* __restrict__ kcat)
{
    __shared__ float row[1344];
    __shared__ float red[4];
    const int t = blockIdx.x, tid = threadIdx.x;
    const long S = 2752512L; // 2048*1344
    const unsigned short* b0 = p + (size_t)t * 1344;
    for (int c = tid; c < 1344; c += 256){
        float v = b2f(b0[c]) + b2f(b0[c + S]) + b2f(b0[c + 2*S]) + b2f(b0[c + 3*S]);
        v += (c < 768) ? q_down_b[c] : kv_down_b[c - 768];
        row[c] = v;
    }
    __syncthreads();
    const int lane = tid & 63, w = tid >> 6;
    float ss = 0.f;
    for (int c = tid; c < 768; c += 256){ float v = row[c]; ss += v * v; }
    #pragma unroll
    for (int o = 32; o > 0; o >>= 1) ss += __shfl_xor(ss, o, 64);
    if (lane == 0) red[w] = ss;
    __syncthreads();
    const float inv1 = rsqrtf((red[0]+red[1]+red[2]+red[3]) / 768.f + 1e-6f);
    __syncthreads();
    ss = 0.f;
    for (int c = tid; c < 512; c += 256){ float v = row[768 + c]; ss += v * v; }
    #pragma unroll
    for (int o = 32; o > 0; o >>= 1) ss += __shfl_xor(ss, o, 64);
    if (lane == 0) red[w] = ss;
    __syncthreads();
    const float inv2 = rsqrtf((red[0]+red[1]+red[2]+red[3]) / 512.f + 1e-6f);
    for (int c = tid; c < 768; c += 256)
        qn[(size_t)t * 768 + c] = f2b(q_norm_s[c] * row[c] * inv1);
    for (int c = tid; c < 512; c += 256)
        kcat[(size_t)t * 576 + c] = f2b(kv_norm_s[c] * row[768 + c] * inv2);
    if (tid < 64){
        const int d = tid, s = t & 1023;
        float x  = row[1280 + d];
        float xp = (d < 32) ? -row[1280 + d + 32] : row[1280 + d - 32];
        float ang = (float)s * powf(10000.f, -(float)(2 * (d & 31)) / 64.f);
        kcat[(size_t)t * 576 + 512 + d] = f2b(x * cosf(ang) + xp * sinf(ang));
    }
}

// out = p[0] + p[1] + bias (p bf16 partials, out f32 2048x2048)
__global__ __launch_bounds__(256) void reduce_out(
    const unsigned short* __restrict__ p, const float* __restrict__ bias,
    float* __restrict__ out)
{
    const long S = 4194304L;
    long i = (long)(blockIdx.x * 256 + threadIdx.x) * 4;
    ushort4 a = *(const ushort4*)(p + i);
    ushort4 b = *(const ushort4*)(p + i + S);
    float4 bb = *(const float4*)(bias + (i & 2047));
    float4 r = make_float4(b2f(a.x) + b2f(b.x) + bb.x, b2f(a.y) + b2f(b.y) + bb.y,
                           b2f(a.z) + b2f(b.z) + bb.z, b2f(a.w) + b2f(b.w) + bb.w);
    *(float4*)(out + i) = r;
}

// Combined: (1) pairwise in-place RoPE on qu's q_rot slices (thread owns the
// (d, d+32) pair -> no race); (2) broadcast roped k_rot into khcat cols 128..192.
__global__ __launch_bounds__(256) void rope_q_krot(
    unsigned short* __restrict__ qu,          // [2048][3072]
    const unsigned short* __restrict__ kcat,  // [2048][576]
    unsigned short* __restrict__ khcat)       // [32][1024][192]
{
    long idx = (long)blockIdx.x * 256 + threadIdx.x;
    if (idx < 1048576L){
        const int d   = idx & 31;
        const int h   = (idx >> 5) & 15;
        const int tok = idx >> 9;
        const int s   = tok & 1023;
        unsigned short* base = qu + (size_t)tok * 3072 + h * 192 + 128;
        float x1 = b2f(base[d]), x2 = b2f(base[d + 32]);
        float ang = (float)s * powf(10000.f, -(float)d / 32.f);
        float c = cosf(ang), sn = sinf(ang);
        base[d]      = f2b(x1 * c - x2 * sn);
        base[d + 32] = f2b(x2 * c + x1 * sn);
    } else {
        idx -= 1048576L;
        const int d   = idx & 63;
        const int h   = (idx >> 6) & 15;
        const int tok = (int)(idx >> 10);
        const int bb  = tok >> 10, s = tok & 1023;
        khcat[((size_t)(bb * 16 + h) * 1024 + s) * 192 + 128 + d] =
            kcat[(size_t)tok * 576 + 512 + d];
    }
}

extern "C" void kernel_launch(void* const* d_in, const int* in_sizes, int n_in,
                              void* d_out, int out_size, void* d_ws, size_t ws_size,
                              hipStream_t stream)
{
    const float* x         = (const float*)d_in[0];
    const float* q_down_w  = (const float*)d_in[3];
    const float* q_down_b  = (const float*)d_in[4];
    const float* q_norm_s  = (const float*)d_in[5];
    const float* q_up_w    = (const float*)d_in[6];
    const float* q_up_b    = (const float*)d_in[7];
    const float* kv_down_w = (const float*)d_in[8];
    const float* kv_down_b = (const float*)d_in[9];
    const float* kv_norm_s = (const float*)d_in[10];
    const float* kv_up_w   = (const float*)d_in[11];
    const float* out_w     = (const float*)d_in[12];
    const float* out_b     = (const float*)d_in[13];
    float* out = (float*)d_out;

    // Workspace layout (bytes), peak 100,925,440:
    char* ws = (char*)d_ws;
    unsigned short* kvuw  = (unsigned short*)(ws + 0);           // [4096][512] (w_k rows 0..2047, w_v 2048..4095)
    unsigned short* outw  = (unsigned short*)(ws + 4194304);     // [2048][2048]
    unsigned short* kcat  = (unsigned short*)(ws + 12582912);    // [2048][576]
    unsigned short* vhT   = (unsigned short*)(ws + 14942208);    // [2][16][128][1024]
    unsigned short* khcat = (unsigned short*)(ws + 23330816);    // [32][1024][192]
    unsigned short* ctx   = (unsigned short*)(ws + 35913728);    // [2048][2048] bf16
    unsigned short* qu    = (unsigned short*)(ws + 44302336);    // [2048][3072] (live through flash)
    unsigned short* qn    = (unsigned short*)(ws + 56885248);    // [2048][768]
    unsigned short* p_qkv = (unsigned short*)(ws + 60030976);    // [4][2048][1344] bf16 (dead after fdp)
    unsigned short* p_out = (unsigned short*)(ws + 60030976);    // [2][2048][2048] bf16 (alias p_qkv)
    unsigned short* xb    = (unsigned short*)(ws + 82051072);    // [2048][2048]
    unsigned short* qkdw  = (unsigned short*)(ws + 90439680);    // [1408][2048] concat down-proj w
    unsigned short* quw   = (unsigned short*)(ws + 96206848);    // [3072][768]

    dim3 blk(256);

    // casts: q_down -> qkdw rows 0..767, kv_down -> qkdw rows 768..1343
    cast_all<<<15232, blk, 0, stream>>>(x, xb, q_down_w, qkdw, q_up_w, quw,
                                        kv_down_w, qkdw + 1572864, kv_up_w, kvuw, out_w, outw);

    // k1 (split-K x4, bf16 partials): p_qkv[s] = x[:, s*512:] @ qkdw[:, s*512:]^T
    mfma_gemm_bt<unsigned short><<<dim3(11, 16, 4), blk, 0, stream>>>(
        xb, qkdw, nullptr, p_qkv, 2048, 1344, 512, 2048, 2048, 1344,
        4, 0L, 512L, 0L, 512L, 0L, 2752512L, 1.0f, 0);
    // fused: partial-sum + biases + q-rmsnorm -> qn, kv-rmsnorm/rope -> kcat
    fused_down_post<<<2048, blk, 0, stream>>>(p_qkv, q_down_b, kv_down_b,
                                              q_norm_s, kv_norm_s, qn, kcat);
    // k3: qu = bf16(qn @ q_up_w^T + b)  [2048,3072] K=768
    mfma_gemm_bt<unsigned short><<<dim3(24, 16, 1), blk, 0, stream>>>(
        qn, quw, q_up_b, qu, 2048, 3072, 768, 768, 768, 3072,
        1, 0, 0, 0, 0, 0, 0, 1.0f, 0);
    // merged vhT + kh: 512 parity-interleaved blocks (was 2x256-block launches)
    mfma_gemm_vk<<<dim3(64, 8, 1), blk, 0, stream>>>(kvuw, kcat, vhT, khcat);
    // rope q (in-place on qu) + broadcast roped k_rot into khcat cols 128..192
    rope_q_krot<<<12288, blk, 0, stream>>>(qu, kcat, khcat);
    // fused attention v9: XCD-local z + complementary backfill
    flash_attn<<<dim3(512), blk, 0, stream>>>(qu, khcat, vhT, ctx);
    // k11 (split-K x2, bf16 partials, 512 blocks): p_out[s] = ctx[:, s*1024:] @ outw[:, s*1024:]^T
    mfma_gemm_bt<unsigned short><<<dim3(16, 16, 2), blk, 0, stream>>>(
        ctx, outw, nullptr, p_out, 2048, 2048, 1024, 2048, 2048, 2048,
        2, 0L, 1024L, 0L, 1024L, 0L, 4194304L, 1.0f, 0);
    // out = p_out[0] + p_out[1] + out_b
    reduce_out<<<4096, blk, 0, stream>>>(p_out, out_b, out);
}